// Round 1
// baseline (984.366 us; speedup 1.0000x reference)
//
#include <hip/hip_runtime.h>
#include <hip/hip_bf16.h>

#define B_  2
#define L_  2048
#define HS_ 2048
#define NH_ 16
#define NKV_ 4
#define HD_ 128
#define EPS_ 1e-6f
#define SCALE_ 0.08838834764831843f
#define LOG2E_ 1.4426950408889634f

typedef __attribute__((ext_vector_type(8))) short bf16x8;
typedef __attribute__((ext_vector_type(4))) float f32x4;

__device__ __forceinline__ f32x4 mfma16(bf16x8 a, bf16x8 b, f32x4 c) {
    return __builtin_amdgcn_mfma_f32_16x16x32_bf16(a, b, c, 0, 0, 0);
}

__device__ __forceinline__ void async_copy16(void* lds, const void* g) {
    __builtin_amdgcn_global_load_lds(
        (const __attribute__((address_space(1))) unsigned int*)g,
        (__attribute__((address_space(3))) unsigned int*)lds,
        16, 0, 0);
}

// ---------------------------------------------------------------------------
// f32 -> bf16 elementwise convert (vectorized x4)
__global__ __launch_bounds__(256) void cvt_f32_bf16(const float* __restrict__ src,
                                                    __hip_bfloat16* __restrict__ dst,
                                                    int n4) {
    int i = blockIdx.x * 256 + threadIdx.x;
    if (i >= n4) return;
    float4 v = ((const float4*)src)[i];
    union { __hip_bfloat16 h[4]; short4 s; } u;
    u.h[0] = __float2bfloat16(v.x);
    u.h[1] = __float2bfloat16(v.y);
    u.h[2] = __float2bfloat16(v.z);
    u.h[3] = __float2bfloat16(v.w);
    ((short4*)dst)[i] = u.s;
}

// ---------------------------------------------------------------------------
// W [K,N] f32  ->  Wt [N,K] bf16 (tiled transpose)
__global__ __launch_bounds__(256) void transpose_cvt(const float* __restrict__ src,
                                                     __hip_bfloat16* __restrict__ dst,
                                                     int K, int N) {
    __shared__ float tile[32][33];
    int n0 = blockIdx.x * 32, k0 = blockIdx.y * 32;
    int tx = threadIdx.x & 31, ty = threadIdx.x >> 5;  // ty: 0..7
#pragma unroll
    for (int i = 0; i < 32; i += 8)
        tile[ty + i][tx] = src[(size_t)(k0 + ty + i) * N + n0 + tx];
    __syncthreads();
#pragma unroll
    for (int i = 0; i < 32; i += 8)
        dst[(size_t)(n0 + ty + i) * K + k0 + tx] = __float2bfloat16(tile[tx][ty + i]);
}

// ---------------------------------------------------------------------------
// V [B,L,NKV,HD] f32 -> Vt [B,NKV,HD,L] bf16 (tiled transpose over (l,d))
__global__ __launch_bounds__(256) void v_transpose(const float* __restrict__ V,
                                                   __hip_bfloat16* __restrict__ Vt) {
    __shared__ float tile[32][33];
    int bkv = blockIdx.z;
    int b = bkv >> 2, kv = bkv & 3;
    int l0 = blockIdx.x * 32, d0 = blockIdx.y * 32;
    int tx = threadIdx.x & 31, ty = threadIdx.x >> 5;
#pragma unroll
    for (int i = 0; i < 32; i += 8)
        tile[ty + i][tx] = V[((size_t)(b * L_ + l0 + ty + i) * NKV_ + kv) * HD_ + d0 + tx];
    __syncthreads();
#pragma unroll
    for (int i = 0; i < 32; i += 8)
        Vt[((size_t)(b * NKV_ + kv) * HD_ + d0 + ty + i) * L_ + l0 + tx] =
            __float2bfloat16(tile[tx][ty + i]);
}

// ---------------------------------------------------------------------------
// GEMM: C[M,N] f32 = A[M,K] bf16 @ Bt[N,K]^T bf16.  128x128 tile, BK=64,
// 4 waves x (64x64), mfma 16x16x32 bf16, global_load_lds width-16 staging.
#define BM 128
#define BN 128
#define BKK 64
__global__ __launch_bounds__(256, 2) void gemm_bf16(const __hip_bfloat16* __restrict__ A,
                                                    const __hip_bfloat16* __restrict__ Bt,
                                                    float* __restrict__ C,
                                                    int M, int N, int K) {
    __shared__ __align__(16) __hip_bfloat16 sA[BM * BKK];
    __shared__ __align__(16) __hip_bfloat16 sB[BN * BKK];
    int t = threadIdx.x;
    int wave = t >> 6, lane = t & 63;
    int row16 = lane & 15, quad = lane >> 4;
    int m0 = blockIdx.x * BM, n0 = blockIdx.y * BN;
    int waveM = (wave >> 1) * 64, waveN = (wave & 1) * 64;
    f32x4 acc[4][4] = {};

    for (int k0 = 0; k0 < K; k0 += BKK) {
#pragma unroll
        for (int i = 0; i < 4; ++i) {
            int c = i * 256 + t;
            int r = c >> 3, kc = (c & 7) * 8;
            async_copy16(&sA[c * 8], A + (size_t)(m0 + r) * K + k0 + kc);
            async_copy16(&sB[c * 8], Bt + (size_t)(n0 + r) * K + k0 + kc);
        }
        __syncthreads();
#pragma unroll
        for (int kc = 0; kc < 2; ++kc) {
            bf16x8 a[4], b[4];
#pragma unroll
            for (int i = 0; i < 4; ++i)
                a[i] = *(const bf16x8*)&sA[(waveM + i * 16 + row16) * BKK + kc * 32 + quad * 8];
#pragma unroll
            for (int j = 0; j < 4; ++j)
                b[j] = *(const bf16x8*)&sB[(waveN + j * 16 + row16) * BKK + kc * 32 + quad * 8];
#pragma unroll
            for (int i = 0; i < 4; ++i)
#pragma unroll
                for (int j = 0; j < 4; ++j)
                    acc[i][j] = mfma16(a[i], b[j], acc[i][j]);
        }
        __syncthreads();
    }
#pragma unroll
    for (int i = 0; i < 4; ++i)
#pragma unroll
        for (int j = 0; j < 4; ++j) {
            int rbase = m0 + waveM + i * 16 + quad * 4;
            int col = n0 + waveN + j * 16 + row16;
#pragma unroll
            for (int r = 0; r < 4; ++r)
                C[(size_t)(rbase + r) * N + col] = acc[i][j][r];
        }
}

// ---------------------------------------------------------------------------
// Per-head RMSNorm + RoPE, f32 in -> bf16 out. One wave per 128-elem row.
// X layout [B*L, nh, 128]. lane handles elements (lane, lane+64).
__global__ __launch_bounds__(256) void norm_rope(const float* __restrict__ X,
                                                 __hip_bfloat16* __restrict__ Y,
                                                 const float* __restrict__ w,
                                                 int log2nh) {
    int row = blockIdx.x * 4 + (threadIdx.x >> 6);
    int lane = threadIdx.x & 63;
    int pos = (row >> log2nh) & (L_ - 1);
    const float* x = X + (size_t)row * HD_;
    float x1 = x[lane], x2 = x[lane + 64];
    float ss = x1 * x1 + x2 * x2;
#pragma unroll
    for (int m = 1; m < 64; m <<= 1) ss += __shfl_xor(ss, m);
    float rms = rsqrtf(ss * (1.0f / 128.0f) + EPS_);
    float xn1 = x1 * rms * w[lane];
    float xn2 = x2 * rms * w[lane + 64];
    float inv_freq = 1.0f / powf(10000.0f, (float)lane * (1.0f / 64.0f));
    float ang = (float)pos * inv_freq;
    float c = cosf(ang), s = sinf(ang);
    __hip_bfloat16* y = Y + (size_t)row * HD_;
    y[lane]      = __float2bfloat16(xn1 * c - xn2 * s);
    y[lane + 64] = __float2bfloat16(xn2 * c + xn1 * s);
}

// ---------------------------------------------------------------------------
// Flash attention (causal, GQA kv = h & 3).
// grid (L/64, NH, B), block 256 = 4 waves; each wave owns 16 q rows.
__global__ __launch_bounds__(256, 2) void flash_attn(const __hip_bfloat16* __restrict__ Q,
                                                     const __hip_bfloat16* __restrict__ Kb,
                                                     const __hip_bfloat16* __restrict__ Vt,
                                                     __hip_bfloat16* __restrict__ O) {
    __shared__ __align__(16) __hip_bfloat16 sP[4][16 * 72];
    int t = threadIdx.x, wave = t >> 6, lane = t & 63;
    int row16 = lane & 15, quad = lane >> 4;
    int h = blockIdx.y, b = blockIdx.z;
    int kv = h & (NKV_ - 1);
    int q0 = blockIdx.x * 64 + wave * 16;

    // Q fragments: A-operand layout, m = lane&15, k = kc*32 + quad*8 + j
    bf16x8 qf[4];
    const __hip_bfloat16* qbase =
        Q + ((size_t)(b * L_ + q0 + row16) * NH_ + h) * HD_ + quad * 8;
#pragma unroll
    for (int kc = 0; kc < 4; ++kc) qf[kc] = *(const bf16x8*)(qbase + kc * 32);

    f32x4 accO[8] = {};
    float mrow[4], lrow[4];
#pragma unroll
    for (int r = 0; r < 4; ++r) { mrow[r] = -1e30f; lrow[r] = 0.f; }
    __hip_bfloat16* myP = &sP[wave][0];

    int ktiles = (q0 >> 6) + 1;
    for (int kt = 0; kt < ktiles; ++kt) {
        int kbase = kt * 64;
        // ---- S = Q K^T for 64 keys (4 blocks of 16)
        f32x4 s[4];
#pragma unroll
        for (int kb = 0; kb < 4; ++kb) {
            f32x4 accS = {};
            const __hip_bfloat16* kptr =
                Kb + ((size_t)(b * L_ + kbase + kb * 16 + row16) * NKV_ + kv) * HD_ + quad * 8;
#pragma unroll
            for (int kc = 0; kc < 4; ++kc) {
                bf16x8 kf = *(const bf16x8*)(kptr + kc * 32);
                accS = mfma16(qf[kc], kf, accS);
            }
            s[kb] = accS;
        }
        // ---- online softmax (row = q0 + quad*4 + r, col = kbase + kb*16 + (lane&15))
        float alpha[4];
#pragma unroll
        for (int r = 0; r < 4; ++r) {
            int qg = q0 + quad * 4 + r;
            float mx = -1e30f;
#pragma unroll
            for (int kb = 0; kb < 4; ++kb) {
                int kg = kbase + kb * 16 + row16;
                float v = s[kb][r] * SCALE_;
                if (kg > qg) v = -1e30f;
                s[kb][r] = v;
                mx = fmaxf(mx, v);
            }
#pragma unroll
            for (int m = 1; m < 16; m <<= 1) mx = fmaxf(mx, __shfl_xor(mx, m));
            float mnew = fmaxf(mrow[r], mx);
            alpha[r] = exp2f((mrow[r] - mnew) * LOG2E_);
            float lsum = 0.f;
#pragma unroll
            for (int kb = 0; kb < 4; ++kb) {
                float p = exp2f((s[kb][r] - mnew) * LOG2E_);
                s[kb][r] = p;
                lsum += p;
            }
#pragma unroll
            for (int m = 1; m < 16; m <<= 1) lsum += __shfl_xor(lsum, m);
            lrow[r] = lrow[r] * alpha[r] + lsum;
            mrow[r] = mnew;
        }
        // rescale O accumulator
#pragma unroll
        for (int db = 0; db < 8; ++db)
#pragma unroll
            for (int r = 0; r < 4; ++r) accO[db][r] *= alpha[r];
        // ---- P (C-layout) -> LDS -> A-layout fragments
#pragma unroll
        for (int r = 0; r < 4; ++r)
#pragma unroll
            for (int kb = 0; kb < 4; ++kb)
                myP[(quad * 4 + r) * 72 + kb * 16 + row16] = __float2bfloat16(s[kb][r]);
        asm volatile("s_waitcnt lgkmcnt(0)" ::: "memory");
        bf16x8 pf[2];
#pragma unroll
        for (int kc2 = 0; kc2 < 2; ++kc2)
            pf[kc2] = *(const bf16x8*)&myP[row16 * 72 + kc2 * 32 + quad * 8];
        // ---- O += P V ; B-operand from Vt[d][key]
#pragma unroll
        for (int db = 0; db < 8; ++db) {
            const __hip_bfloat16* vptr =
                Vt + ((size_t)(b * NKV_ + kv) * HD_ + db * 16 + row16) * L_ + kbase + quad * 8;
#pragma unroll
            for (int kc2 = 0; kc2 < 2; ++kc2) {
                bf16x8 vf = *(const bf16x8*)(vptr + kc2 * 32);
                accO[db] = mfma16(pf[kc2], vf, accO[db]);
            }
        }
    }
    // ---- epilogue: normalize and store bf16 [B,L,NH,HD]
    float linv[4];
#pragma unroll
    for (int r = 0; r < 4; ++r) linv[r] = 1.0f / lrow[r];
#pragma unroll
    for (int db = 0; db < 8; ++db)
#pragma unroll
        for (int r = 0; r < 4; ++r) {
            int qg = q0 + quad * 4 + r;
            O[((size_t)(b * L_ + qg) * NH_ + h) * HD_ + db * 16 + row16] =
                __float2bfloat16(accO[db][r] * linv[r]);
        }
}

// ---------------------------------------------------------------------------
extern "C" void kernel_launch(void* const* d_in, const int* in_sizes, int n_in,
                              void* d_out, int out_size, void* d_ws, size_t ws_size,
                              hipStream_t stream) {
    const float* hidden = (const float*)d_in[0];
    const float* Wq = (const float*)d_in[1];
    const float* Wk = (const float*)d_in[2];
    const float* Wv = (const float*)d_in[3];
    const float* Wo = (const float*)d_in[4];
    const float* qw = (const float*)d_in[5];
    const float* kw = (const float*)d_in[6];
    float* out = (float*)d_out;

    char* ws = (char*)d_ws;
    size_t off = 0;
    auto alloc = [&](size_t bytes) { char* p = ws + off; off += (bytes + 255) & ~255ull; return p; };
    __hip_bfloat16* Wq_t = (__hip_bfloat16*)alloc((size_t)HS_ * NH_ * HD_ * 2);   // [2048,2048]
    __hip_bfloat16* Wk_t = (__hip_bfloat16*)alloc((size_t)HS_ * NKV_ * HD_ * 2);  // [512,2048]
    __hip_bfloat16* Wv_t = (__hip_bfloat16*)alloc((size_t)HS_ * NKV_ * HD_ * 2);
    __hip_bfloat16* Wo_t = (__hip_bfloat16*)alloc((size_t)HS_ * NH_ * HD_ * 2);
    __hip_bfloat16* A_h  = (__hip_bfloat16*)alloc((size_t)B_ * L_ * HS_ * 2);     // hidden bf16; reused as attn_bf
    float* k_f32 = (float*)alloc((size_t)B_ * L_ * NKV_ * HD_ * 4);
    float* v_f32 = (float*)alloc((size_t)B_ * L_ * NKV_ * HD_ * 4);
    __hip_bfloat16* q_bf = (__hip_bfloat16*)alloc((size_t)B_ * L_ * NH_ * HD_ * 2);
    __hip_bfloat16* k_bf = (__hip_bfloat16*)alloc((size_t)B_ * L_ * NKV_ * HD_ * 2);
    __hip_bfloat16* vt_bf = (__hip_bfloat16*)alloc((size_t)B_ * NKV_ * HD_ * L_ * 2);
    float* q_f32 = out;  // reuse d_out as scratch for pre-norm Q
    __hip_bfloat16* attn_bf = A_h;  // reuse after QKV gemms complete

    const int M = B_ * L_;  // 4096

    // 1. hidden -> bf16
    cvt_f32_bf16<<<(M * HS_ / 4 + 255) / 256, 256, 0, stream>>>(hidden, A_h, M * HS_ / 4);
    // 2. weight transposes -> [N,K] bf16
    transpose_cvt<<<dim3(2048 / 32, 2048 / 32), 256, 0, stream>>>(Wq, Wq_t, HS_, 2048);
    transpose_cvt<<<dim3(512 / 32, 2048 / 32), 256, 0, stream>>>(Wk, Wk_t, HS_, 512);
    transpose_cvt<<<dim3(512 / 32, 2048 / 32), 256, 0, stream>>>(Wv, Wv_t, HS_, 512);
    transpose_cvt<<<dim3(2048 / 32, 2048 / 32), 256, 0, stream>>>(Wo, Wo_t, HS_, 2048);
    // 3. QKV projections
    gemm_bf16<<<dim3(M / BM, 2048 / BN), 256, 0, stream>>>(A_h, Wq_t, q_f32, M, 2048, HS_);
    gemm_bf16<<<dim3(M / BM, 512 / BN), 256, 0, stream>>>(A_h, Wk_t, k_f32, M, 512, HS_);
    gemm_bf16<<<dim3(M / BM, 512 / BN), 256, 0, stream>>>(A_h, Wv_t, v_f32, M, 512, HS_);
    // 4. RMSNorm + RoPE -> bf16
    norm_rope<<<(M * NH_) / 4, 256, 0, stream>>>(q_f32, q_bf, qw, 4);
    norm_rope<<<(M * NKV_) / 4, 256, 0, stream>>>(k_f32, k_bf, kw, 2);
    // 5. V -> Vt bf16 [B,NKV,HD,L]
    v_transpose<<<dim3(L_ / 32, HD_ / 32, B_ * NKV_), 256, 0, stream>>>(v_f32, vt_bf);
    // 6. attention
    flash_attn<<<dim3(L_ / 64, NH_, B_), 256, 0, stream>>>(q_bf, k_bf, vt_bf, attn_bf);
    // 7. output projection
    gemm_bf16<<<dim3(M / BM, 2048 / BN), 256, 0, stream>>>(attn_bf, Wo_t, out, M, 2048, HS_);
}

// Round 2
// 479.660 us; speedup vs baseline: 2.0522x; 2.0522x over previous
//
#include <hip/hip_runtime.h>
#include <hip/hip_bf16.h>

#define B_  2
#define L_  2048
#define HS_ 2048
#define NH_ 16
#define NKV_ 4
#define HD_ 128
#define EPS_ 1e-6f
#define SCALE_ 0.08838834764831843f
#define LOG2E_ 1.4426950408889634f

typedef __attribute__((ext_vector_type(8))) short bf16x8;
typedef __attribute__((ext_vector_type(4))) float f32x4;

__device__ __forceinline__ f32x4 mfma16(bf16x8 a, bf16x8 b, f32x4 c) {
    return __builtin_amdgcn_mfma_f32_16x16x32_bf16(a, b, c, 0, 0, 0);
}

__device__ __forceinline__ void async_copy16(void* lds, const void* g) {
    __builtin_amdgcn_global_load_lds(
        (const __attribute__((address_space(1))) unsigned int*)g,
        (__attribute__((address_space(3))) unsigned int*)lds,
        16, 0, 0);
}

// ---------------------------------------------------------------------------
__global__ __launch_bounds__(256) void cvt_f32_bf16(const float* __restrict__ src,
                                                    __hip_bfloat16* __restrict__ dst,
                                                    int n4) {
    int i = blockIdx.x * 256 + threadIdx.x;
    if (i >= n4) return;
    float4 v = ((const float4*)src)[i];
    union { __hip_bfloat16 h[4]; short4 s; } u;
    u.h[0] = __float2bfloat16(v.x);
    u.h[1] = __float2bfloat16(v.y);
    u.h[2] = __float2bfloat16(v.z);
    u.h[3] = __float2bfloat16(v.w);
    ((short4*)dst)[i] = u.s;
}

// ---------------------------------------------------------------------------
__global__ __launch_bounds__(256) void transpose_cvt(const float* __restrict__ src,
                                                     __hip_bfloat16* __restrict__ dst,
                                                     int K, int N) {
    __shared__ float tile[32][33];
    int n0 = blockIdx.x * 32, k0 = blockIdx.y * 32;
    int tx = threadIdx.x & 31, ty = threadIdx.x >> 5;
#pragma unroll
    for (int i = 0; i < 32; i += 8)
        tile[ty + i][tx] = src[(size_t)(k0 + ty + i) * N + n0 + tx];
    __syncthreads();
#pragma unroll
    for (int i = 0; i < 32; i += 8)
        dst[(size_t)(n0 + ty + i) * K + k0 + tx] = __float2bfloat16(tile[tx][ty + i]);
}

// ---------------------------------------------------------------------------
__global__ __launch_bounds__(256) void v_transpose(const float* __restrict__ V,
                                                   __hip_bfloat16* __restrict__ Vt) {
    __shared__ float tile[32][33];
    int bkv = blockIdx.z;
    int b = bkv >> 2, kv = bkv & 3;
    int l0 = blockIdx.x * 32, d0 = blockIdx.y * 32;
    int tx = threadIdx.x & 31, ty = threadIdx.x >> 5;
#pragma unroll
    for (int i = 0; i < 32; i += 8)
        tile[ty + i][tx] = V[((size_t)(b * L_ + l0 + ty + i) * NKV_ + kv) * HD_ + d0 + tx];
    __syncthreads();
#pragma unroll
    for (int i = 0; i < 32; i += 8)
        Vt[((size_t)(b * NKV_ + kv) * HD_ + d0 + ty + i) * L_ + l0 + tx] =
            __float2bfloat16(tile[tx][ty + i]);
}

// ---------------------------------------------------------------------------
#define BM 128
#define BN 128
#define BKK 64
__global__ __launch_bounds__(256, 2) void gemm_bf16(const __hip_bfloat16* __restrict__ A,
                                                    const __hip_bfloat16* __restrict__ Bt,
                                                    float* __restrict__ C,
                                                    int M, int N, int K) {
    __shared__ __align__(16) __hip_bfloat16 sA[BM * BKK];
    __shared__ __align__(16) __hip_bfloat16 sB[BN * BKK];
    int t = threadIdx.x;
    int wave = t >> 6, lane = t & 63;
    int row16 = lane & 15, quad = lane >> 4;
    int m0 = blockIdx.x * BM, n0 = blockIdx.y * BN;
    int waveM = (wave >> 1) * 64, waveN = (wave & 1) * 64;
    f32x4 acc[4][4] = {};

    for (int k0 = 0; k0 < K; k0 += BKK) {
#pragma unroll
        for (int i = 0; i < 4; ++i) {
            int c = i * 256 + t;
            int r = c >> 3, kc = (c & 7) * 8;
            async_copy16(&sA[c * 8], A + (size_t)(m0 + r) * K + k0 + kc);
            async_copy16(&sB[c * 8], Bt + (size_t)(n0 + r) * K + k0 + kc);
        }
        __syncthreads();
#pragma unroll
        for (int kc = 0; kc < 2; ++kc) {
            bf16x8 a[4], b[4];
#pragma unroll
            for (int i = 0; i < 4; ++i)
                a[i] = *(const bf16x8*)&sA[(waveM + i * 16 + row16) * BKK + kc * 32 + quad * 8];
#pragma unroll
            for (int j = 0; j < 4; ++j)
                b[j] = *(const bf16x8*)&sB[(waveN + j * 16 + row16) * BKK + kc * 32 + quad * 8];
#pragma unroll
            for (int i = 0; i < 4; ++i)
#pragma unroll
                for (int j = 0; j < 4; ++j)
                    acc[i][j] = mfma16(a[i], b[j], acc[i][j]);
        }
        __syncthreads();
    }
#pragma unroll
    for (int i = 0; i < 4; ++i)
#pragma unroll
        for (int j = 0; j < 4; ++j) {
            int rbase = m0 + waveM + i * 16 + quad * 4;
            int col = n0 + waveN + j * 16 + row16;
#pragma unroll
            for (int r = 0; r < 4; ++r)
                C[(size_t)(rbase + r) * N + col] = acc[i][j][r];
        }
}

// ---------------------------------------------------------------------------
__global__ __launch_bounds__(256) void norm_rope(const float* __restrict__ X,
                                                 __hip_bfloat16* __restrict__ Y,
                                                 const float* __restrict__ w,
                                                 int log2nh) {
    int row = blockIdx.x * 4 + (threadIdx.x >> 6);
    int lane = threadIdx.x & 63;
    int pos = (row >> log2nh) & (L_ - 1);
    const float* x = X + (size_t)row * HD_;
    float x1 = x[lane], x2 = x[lane + 64];
    float ss = x1 * x1 + x2 * x2;
#pragma unroll
    for (int m = 1; m < 64; m <<= 1) ss += __shfl_xor(ss, m);
    float rms = rsqrtf(ss * (1.0f / 128.0f) + EPS_);
    float xn1 = x1 * rms * w[lane];
    float xn2 = x2 * rms * w[lane + 64];
    float inv_freq = 1.0f / powf(10000.0f, (float)lane * (1.0f / 64.0f));
    float ang = (float)pos * inv_freq;
    float c = cosf(ang), s = sinf(ang);
    __hip_bfloat16* y = Y + (size_t)row * HD_;
    y[lane]      = __float2bfloat16(xn1 * c - xn2 * s);
    y[lane + 64] = __float2bfloat16(xn2 * c + xn1 * s);
}

// ---------------------------------------------------------------------------
// Flash attention v2: S^T = K Q^T (per-lane softmax over in-register keys),
// O^T = V^T P^T, K/V tiles staged in LDS (shared by 4 waves) double-buffered
// via global_load_lds with XOR chunk swizzle; one barrier per key-tile.
// grid (32, NH, B) with reversed q-tile order; block 256 = 4 waves x 16 q.
__global__ __launch_bounds__(256, 2) void flash_attn(const __hip_bfloat16* __restrict__ Q,
                                                     const __hip_bfloat16* __restrict__ Kb,
                                                     const __hip_bfloat16* __restrict__ Vt,
                                                     __hip_bfloat16* __restrict__ O) {
    __shared__ __align__(16) __hip_bfloat16 sK[2][64 * 128];   // [key][dim], swizzled 16B chunks
    __shared__ __align__(16) __hip_bfloat16 sV[2][128 * 64];   // [dim][key], swizzled 16B chunks
    __shared__ __align__(16) __hip_bfloat16 sP[4][16 * 72];    // per-wave P [q][key], +8 pad

    int t = threadIdx.x, wave = t >> 6, lane = t & 63;
    int row16 = lane & 15, quad = lane >> 4;
    int h = blockIdx.y, b = blockIdx.z;
    int kv = h & (NKV_ - 1);
    int qt = gridDim.x - 1 - blockIdx.x;        // longest blocks first
    int q0 = qt * 64;
    int q0w = q0 + wave * 16;
    int ktiles = qt + 1;

    // Q fragments (B-operand): n = q = lane&15, k = kc*32 + quad*8 + j
    bf16x8 qf[4];
    const __hip_bfloat16* qbase =
        Q + ((size_t)(b * L_ + q0w + row16) * NH_ + h) * HD_ + quad * 8;
#pragma unroll
    for (int kc = 0; kc < 4; ++kc) qf[kc] = *(const bf16x8*)(qbase + kc * 32);

    f32x4 accO[8] = {};           // O^T: row d = db*16+quad*4+r, col q = lane&15
    float mrow = -1e30f, lrow = 0.f;
    __hip_bfloat16* myP = &sP[wave][0];

    // stage key-tile kt into buffer buf (4 K insts + 4 V insts per wave)
    auto stage = [&](int buf, int kt) {
        int kbase = kt * 64;
#pragma unroll
        for (int i = 0; i < 4; ++i) {
            int w16 = wave * 4 + i;
            int rk = w16 * 4 + (lane >> 4);                 // K row 0..63
            int ck = (lane & 15) ^ (rk & 7);                // swizzled global chunk
            async_copy16(&sK[buf][w16 * 512 + lane * 8],
                         Kb + ((size_t)(b * L_ + kbase + rk) * NKV_ + kv) * HD_ + ck * 8);
            int rv = w16 * 8 + (lane >> 3);                 // V row (dim) 0..127
            int cv = (lane & 7) ^ (rv & 7);
            async_copy16(&sV[buf][w16 * 512 + lane * 8],
                         Vt + ((size_t)(b * NKV_ + kv) * HD_ + rv) * L_ + kbase + cv * 8);
        }
    };

    stage(0, 0);
    for (int kt = 0; kt < ktiles; ++kt) {
        __syncthreads();                         // publishes buf kt&1 (drains vmcnt)
        if (kt + 1 < ktiles) stage((kt + 1) & 1, kt + 1);
        const __hip_bfloat16* cK = &sK[kt & 1][0];
        const __hip_bfloat16* cV = &sV[kt & 1][0];
        int kbase = kt * 64;

        // ---- S^T = K Q^T : rows = key (quad*4+r per kb), cols = q (lane&15)
        f32x4 st[4];
#pragma unroll
        for (int kb = 0; kb < 4; ++kb) {
            f32x4 acc = {};
#pragma unroll
            for (int kc = 0; kc < 4; ++kc) {
                int rk = kb * 16 + row16;
                int s = (kc * 4 + quad) ^ (rk & 7);
                bf16x8 kf = *(const bf16x8*)&cK[rk * 128 + s * 8];
                acc = mfma16(kf, qf[kc], acc);
            }
            st[kb] = acc;
        }

        // ---- per-lane online softmax (lane owns q = q0w + row16)
        int qg = q0w + row16;
        float p[4][4];
        float mx = -1e30f;
#pragma unroll
        for (int kb = 0; kb < 4; ++kb)
#pragma unroll
            for (int r = 0; r < 4; ++r) {
                int key = kbase + kb * 16 + quad * 4 + r;
                float v = st[kb][r] * SCALE_;
                v = (key <= qg) ? v : -1e30f;
                p[kb][r] = v;
                mx = fmaxf(mx, v);
            }
        mx = fmaxf(mx, __shfl_xor(mx, 16));
        mx = fmaxf(mx, __shfl_xor(mx, 32));
        float mnew = fmaxf(mrow, mx);
        float al = __builtin_exp2f((mrow - mnew) * LOG2E_);
        float lsum = 0.f;
#pragma unroll
        for (int kb = 0; kb < 4; ++kb)
#pragma unroll
            for (int r = 0; r < 4; ++r) {
                float e = __builtin_exp2f((p[kb][r] - mnew) * LOG2E_);
                p[kb][r] = e;
                lsum += e;
            }
        lsum += __shfl_xor(lsum, 16);
        lsum += __shfl_xor(lsum, 32);
        lrow = lrow * al + lsum;
        mrow = mnew;
#pragma unroll
        for (int db = 0; db < 8; ++db)
#pragma unroll
            for (int r = 0; r < 4; ++r) accO[db][r] *= al;

        // ---- P -> LDS [q][key] (packed b64 writes), read back as B-operand P^T
#pragma unroll
        for (int kb = 0; kb < 4; ++kb) {
            union { __hip_bfloat16 h[4]; short4 s4; } u;
#pragma unroll
            for (int r = 0; r < 4; ++r) u.h[r] = __float2bfloat16(p[kb][r]);
            *(short4*)&myP[row16 * 72 + kb * 16 + quad * 4] = u.s4;
        }
        asm volatile("s_waitcnt lgkmcnt(0)" ::: "memory");
        bf16x8 pf[2];
#pragma unroll
        for (int kc2 = 0; kc2 < 2; ++kc2)
            pf[kc2] = *(const bf16x8*)&myP[row16 * 72 + kc2 * 32 + quad * 8];

        // ---- O^T += V^T P^T : A = V-frag (m = d), B = P^T-frag (n = q)
#pragma unroll
        for (int db = 0; db < 8; ++db)
#pragma unroll
            for (int kc2 = 0; kc2 < 2; ++kc2) {
                int rv = db * 16 + row16;
                int s = (kc2 * 4 + quad) ^ (rv & 7);
                bf16x8 vf = *(const bf16x8*)&cV[rv * 64 + s * 8];
                accO[db] = mfma16(vf, pf[kc2], accO[db]);
            }
    }

    // ---- epilogue: O^T col q = lane&15 owns l; store packed 4 d per reg group
    float linv = 1.0f / lrow;
    __hip_bfloat16* obase = O + ((size_t)(b * L_ + q0w + row16) * NH_ + h) * HD_;
#pragma unroll
    for (int db = 0; db < 8; ++db) {
        union { __hip_bfloat16 h[4]; short4 s4; } u;
#pragma unroll
        for (int r = 0; r < 4; ++r) u.h[r] = __float2bfloat16(accO[db][r] * linv);
        *(short4*)(obase + db * 16 + quad * 4) = u.s4;
    }
}

// ---------------------------------------------------------------------------
extern "C" void kernel_launch(void* const* d_in, const int* in_sizes, int n_in,
                              void* d_out, int out_size, void* d_ws, size_t ws_size,
                              hipStream_t stream) {
    const float* hidden = (const float*)d_in[0];
    const float* Wq = (const float*)d_in[1];
    const float* Wk = (const float*)d_in[2];
    const float* Wv = (const float*)d_in[3];
    const float* Wo = (const float*)d_in[4];
    const float* qw = (const float*)d_in[5];
    const float* kw = (const float*)d_in[6];
    float* out = (float*)d_out;

    char* ws = (char*)d_ws;
    size_t off = 0;
    auto alloc = [&](size_t bytes) { char* p = ws + off; off += (bytes + 255) & ~255ull; return p; };
    __hip_bfloat16* Wq_t = (__hip_bfloat16*)alloc((size_t)HS_ * NH_ * HD_ * 2);
    __hip_bfloat16* Wk_t = (__hip_bfloat16*)alloc((size_t)HS_ * NKV_ * HD_ * 2);
    __hip_bfloat16* Wv_t = (__hip_bfloat16*)alloc((size_t)HS_ * NKV_ * HD_ * 2);
    __hip_bfloat16* Wo_t = (__hip_bfloat16*)alloc((size_t)HS_ * NH_ * HD_ * 2);
    __hip_bfloat16* A_h  = (__hip_bfloat16*)alloc((size_t)B_ * L_ * HS_ * 2);
    float* k_f32 = (float*)alloc((size_t)B_ * L_ * NKV_ * HD_ * 4);
    float* v_f32 = (float*)alloc((size_t)B_ * L_ * NKV_ * HD_ * 4);
    __hip_bfloat16* q_bf = (__hip_bfloat16*)alloc((size_t)B_ * L_ * NH_ * HD_ * 2);
    __hip_bfloat16* k_bf = (__hip_bfloat16*)alloc((size_t)B_ * L_ * NKV_ * HD_ * 2);
    __hip_bfloat16* vt_bf = (__hip_bfloat16*)alloc((size_t)B_ * NKV_ * HD_ * L_ * 2);
    float* q_f32 = out;
    __hip_bfloat16* attn_bf = A_h;

    const int M = B_ * L_;

    cvt_f32_bf16<<<(M * HS_ / 4 + 255) / 256, 256, 0, stream>>>(hidden, A_h, M * HS_ / 4);
    transpose_cvt<<<dim3(2048 / 32, 2048 / 32), 256, 0, stream>>>(Wq, Wq_t, HS_, 2048);
    transpose_cvt<<<dim3(512 / 32, 2048 / 32), 256, 0, stream>>>(Wk, Wk_t, HS_, 512);
    transpose_cvt<<<dim3(512 / 32, 2048 / 32), 256, 0, stream>>>(Wv, Wv_t, HS_, 512);
    transpose_cvt<<<dim3(2048 / 32, 2048 / 32), 256, 0, stream>>>(Wo, Wo_t, HS_, 2048);
    gemm_bf16<<<dim3(M / BM, 2048 / BN), 256, 0, stream>>>(A_h, Wq_t, q_f32, M, 2048, HS_);
    gemm_bf16<<<dim3(M / BM, 512 / BN), 256, 0, stream>>>(A_h, Wk_t, k_f32, M, 512, HS_);
    gemm_bf16<<<dim3(M / BM, 512 / BN), 256, 0, stream>>>(A_h, Wv_t, v_f32, M, 512, HS_);
    norm_rope<<<(M * NH_) / 4, 256, 0, stream>>>(q_f32, q_bf, qw, 4);
    norm_rope<<<(M * NKV_) / 4, 256, 0, stream>>>(k_f32, k_bf, kw, 2);
    v_transpose<<<dim3(L_ / 32, HD_ / 32, B_ * NKV_), 256, 0, stream>>>(v_f32, vt_bf);
    flash_attn<<<dim3(L_ / 64, NH_, B_), 256, 0, stream>>>(q_bf, k_bf, vt_bf, attn_bf);
    gemm_bf16<<<dim3(M / BM, 2048 / BN), 256, 0, stream>>>(attn_bf, Wo_t, out, M, 2048, HS_);
}